// Round 2
// baseline (65.146 us; speedup 1.0000x reference)
//
#include <hip/hip_runtime.h>

// Problem constants (from setup_inputs): B=8, N=1024, E=16384, Din=128, U=128
#define B_   8
#define N_   1024
#define E_   16384
#define DIN_ 128
#define U_   128

// ---------------------------------------------------------------------------
// K1: support = x @ kernel   [B*N rows, 128x128 GEMM, fp32 vector ALU]
// 128 threads/block, 8 rows/block, register tiling over rows.
__global__ void k_support(const float* __restrict__ x, const float* __restrict__ kern,
                          float* __restrict__ support) {
    int u = threadIdx.x;               // output channel 0..127
    int row0 = blockIdx.x * 8;
    __shared__ float xs[8][DIN_];
    #pragma unroll
    for (int r = 0; r < 8; ++r) xs[r][u] = x[(size_t)(row0 + r) * DIN_ + u];
    __syncthreads();
    float acc[8] = {0.f, 0.f, 0.f, 0.f, 0.f, 0.f, 0.f, 0.f};
    #pragma unroll 4
    for (int d = 0; d < DIN_; ++d) {
        float k = kern[d * U_ + u];    // coalesced across threads, L2-resident
        #pragma unroll
        for (int r = 0; r < 8; ++r) acc[r] = fmaf(xs[r][d], k, acc[r]);
    }
    #pragma unroll
    for (int r = 0; r < 8; ++r) support[(size_t)(row0 + r) * U_ + u] = acc[r];
}

// ---------------------------------------------------------------------------
// K2: per-batch CSR build, entirely in one block via LDS atomics.
// One 1024-thread block per batch: zero LDS histogram -> count (LDS atomics)
// -> Hillis-Steele scan (LDS) -> isd/offsets/counts out -> counting-sort fill
// (LDS cursor atomics, global bucket writes). No global memset needed.
__global__ void k_build(const int* __restrict__ edge_index, const int* __restrict__ edge_mask,
                        const int* __restrict__ node_mask,
                        int* __restrict__ offsets, int* __restrict__ counts_g,
                        float* __restrict__ isd, int* __restrict__ bucket) {
    int b = blockIdx.x;
    int t = threadIdx.x;               // 0..1023 (= node id for per-node phases)
    __shared__ int cnt[N_];
    __shared__ int scan[N_];
    __shared__ int cur[N_];
    cnt[t] = 0;
    __syncthreads();

    const int* src_p = edge_index + (size_t)b * 2 * E_;
    const int* dst_p = src_p + E_;
    const int* em    = edge_mask + (size_t)b * E_;

    // count in-degree into LDS histogram
    #pragma unroll 4
    for (int e = t; e < E_; e += 1024) {
        if (em[e] != 0) {
            int d = min(max(dst_p[e], 0), N_ - 1);
            atomicAdd(&cnt[d], 1);
        }
    }
    __syncthreads();

    // exclusive scan (Hillis-Steele)
    int c = cnt[t];
    scan[t] = c;
    __syncthreads();
    for (int off = 1; off < N_; off <<= 1) {
        int v = (t >= off) ? scan[t - off] : 0;
        __syncthreads();
        scan[t] += v;
        __syncthreads();
    }
    int excl = scan[t] - c;
    cur[t] = excl;
    offsets[b * N_ + t]  = excl;
    counts_g[b * N_ + t] = c;
    float nm = (node_mask[b * N_ + t] != 0) ? 1.0f : 0.0f;
    isd[b * N_ + t] = rsqrtf(fmaxf((float)c + nm, 1e-6f));
    __syncthreads();

    // counting-sort: scatter edge sources into per-dst buckets
    int* bk = bucket + (size_t)b * E_;
    #pragma unroll 4
    for (int e = t; e < E_; e += 1024) {
        if (em[e] != 0) {
            int s = min(max(src_p[e], 0), N_ - 1);
            int d = min(max(dst_p[e], 0), N_ - 1);
            int pos = atomicAdd(&cur[d], 1);
            bk[pos] = s;
        }
    }
}

// ---------------------------------------------------------------------------
// K3: per-node aggregation. One 128-thread block per (b,n); thread u owns
// output channel u. No fp atomics — CSR bucket walk, fp32 register accumulate.
__global__ void k_agg(const float* __restrict__ support, const int* __restrict__ node_mask,
                      const int* __restrict__ offsets, const int* __restrict__ counts,
                      const float* __restrict__ isd, const int* __restrict__ bucket,
                      const float* __restrict__ bias, float* __restrict__ out) {
    int u  = threadIdx.x;
    int bn = blockIdx.x;               // b*N_ + n
    int b  = bn / N_;
    int start = offsets[bn];
    int cnt   = counts[bn];
    float isd_n = isd[bn];
    int nm = node_mask[bn];
    // self-loop contribution: nm * isd_n * supp[n,u]
    float acc = nm ? isd_n * support[(size_t)bn * U_ + u] : 0.f;
    const int* bk = bucket + (size_t)b * E_;
    for (int t = 0; t < cnt; ++t) {
        int m = bk[start + t];
        acc = fmaf(isd[b * N_ + m], support[(size_t)(b * N_ + m) * U_ + u], acc);
    }
    out[(size_t)bn * U_ + u] = nm ? fmaf(isd_n, acc, bias[u]) : 0.f;
}

// ---------------------------------------------------------------------------
extern "C" void kernel_launch(void* const* d_in, const int* in_sizes, int n_in,
                              void* d_out, int out_size, void* d_ws, size_t ws_size,
                              hipStream_t stream) {
    const float* x         = (const float*)d_in[0];
    const int*   node_mask = (const int*)d_in[1];
    const int*   edge_index= (const int*)d_in[2];
    const int*   edge_mask = (const int*)d_in[3];
    const float* kern      = (const float*)d_in[4];
    const float* bias      = (const float*)d_in[5];
    float*       out       = (float*)d_out;

    char* ws = (char*)d_ws;
    size_t off = 0;
    float* support = (float*)(ws + off); off += (size_t)B_ * N_ * U_ * sizeof(float);
    int*   offsets = (int*)(ws + off);   off += (size_t)B_ * N_ * sizeof(int);
    int*   counts  = (int*)(ws + off);   off += (size_t)B_ * N_ * sizeof(int);
    float* isd     = (float*)(ws + off); off += (size_t)B_ * N_ * sizeof(float);
    int*   bucket  = (int*)(ws + off);   off += (size_t)B_ * E_ * sizeof(int);

    k_support<<<B_ * N_ / 8, 128, 0, stream>>>(x, kern, support);
    k_build<<<B_, N_, 0, stream>>>(edge_index, edge_mask, node_mask,
                                   offsets, counts, isd, bucket);
    k_agg<<<B_ * N_, 128, 0, stream>>>(support, node_mask, offsets, counts, isd, bucket, bias, out);
}

// Round 3
// 52.872 us; speedup vs baseline: 1.2321x; 1.2321x over previous
//
#include <hip/hip_runtime.h>

// Problem constants (from setup_inputs): B=8, N=1024, E=16384, Din=128, U=128
#define B_   8
#define N_   1024
#define E_   16384
#define DIN_ 128
#define U_   128

// ---------------------------------------------------------------------------
// K1: support = x @ kernel   [B*N rows, 128x128 GEMM, fp32 vector ALU]
// 128 threads/block, 8 rows/block, register tiling over rows.
// Also zeros the global `counts` array (8192 ints across 1024 blocks) so no
// hipMemsetAsync fill dispatch is needed before k_count.
__global__ void k_support(const float* __restrict__ x, const float* __restrict__ kern,
                          float* __restrict__ support, int* __restrict__ counts) {
    int u = threadIdx.x;               // output channel 0..127
    int row0 = blockIdx.x * 8;
    // zero 8 counts per block (1024 blocks * 8 = 8192 = B*N)
    if (u < 8) counts[blockIdx.x * 8 + u] = 0;
    __shared__ float xs[8][DIN_];
    #pragma unroll
    for (int r = 0; r < 8; ++r) xs[r][u] = x[(size_t)(row0 + r) * DIN_ + u];
    __syncthreads();
    float acc[8] = {0.f, 0.f, 0.f, 0.f, 0.f, 0.f, 0.f, 0.f};
    #pragma unroll 4
    for (int d = 0; d < DIN_; ++d) {
        float k = kern[d * U_ + u];    // coalesced across threads, L2-resident
        #pragma unroll
        for (int r = 0; r < 8; ++r) acc[r] = fmaf(xs[r][d], k, acc[r]);
    }
    #pragma unroll
    for (int r = 0; r < 8; ++r) support[(size_t)(row0 + r) * U_ + u] = acc[r];
}

// ---------------------------------------------------------------------------
// K2: in-degree counts per (b, dst) via global int atomics. 512 blocks.
__global__ void k_count(const int* __restrict__ edge_index, const int* __restrict__ edge_mask,
                        int* __restrict__ counts) {
    int i = blockIdx.x * blockDim.x + threadIdx.x;   // flat b*E + e
    if (i >= B_ * E_) return;
    int b = i / E_, e = i - b * E_;
    if (edge_mask[i] != 0) {
        int dst = edge_index[b * 2 * E_ + E_ + e];   // edge_index[b,1,e]
        dst = min(max(dst, 0), N_ - 1);
        atomicAdd(&counts[b * N_ + dst], 1);
    }
}

// ---------------------------------------------------------------------------
// K3: per-batch exclusive scan of counts (CSR offsets) + isd.
// One block per batch, 1024 threads = 16 waves. shfl-based scan: 6 shfl steps
// per wave + 2 barriers (vs 20 barriers for LDS Hillis-Steele).
__global__ void k_scan(const int* __restrict__ counts, const int* __restrict__ node_mask,
                       int* __restrict__ offsets, int* __restrict__ cursor,
                       float* __restrict__ isd) {
    int b = blockIdx.x, t = threadIdx.x;
    int lane = t & 63, wid = t >> 6;
    int c = counts[b * N_ + t];
    // inclusive scan within wave
    int v = c;
    #pragma unroll
    for (int off = 1; off < 64; off <<= 1) {
        int s = __shfl_up(v, off, 64);
        if (lane >= off) v += s;
    }
    __shared__ int wsum[16];
    if (lane == 63) wsum[wid] = v;
    __syncthreads();
    if (wid == 0 && lane < 16) {
        int s = wsum[lane];
        #pragma unroll
        for (int off = 1; off < 16; off <<= 1) {
            int z = __shfl_up(s, off, 64);
            if (lane >= off) s += z;
        }
        wsum[lane] = s;                // inclusive wave-total prefix
    }
    __syncthreads();
    int base = (wid > 0) ? wsum[wid - 1] : 0;
    int excl = base + v - c;
    offsets[b * N_ + t] = excl;
    cursor[b * N_ + t]  = excl;
    float nm  = (node_mask[b * N_ + t] != 0) ? 1.0f : 0.0f;
    isd[b * N_ + t] = rsqrtf(fmaxf((float)c + nm, 1e-6f));
}

// ---------------------------------------------------------------------------
// K4: counting-sort edge sources into per-dst buckets. 512 blocks.
__global__ void k_fill(const int* __restrict__ edge_index, const int* __restrict__ edge_mask,
                       int* __restrict__ cursor, int* __restrict__ bucket) {
    int i = blockIdx.x * blockDim.x + threadIdx.x;
    if (i >= B_ * E_) return;
    int b = i / E_, e = i - b * E_;
    if (edge_mask[i] != 0) {
        int src = edge_index[b * 2 * E_ + e];        // edge_index[b,0,e]
        int dst = edge_index[b * 2 * E_ + E_ + e];   // edge_index[b,1,e]
        src = min(max(src, 0), N_ - 1);
        dst = min(max(dst, 0), N_ - 1);
        int pos = atomicAdd(&cursor[b * N_ + dst], 1);
        bucket[b * E_ + pos] = src;
    }
}

// ---------------------------------------------------------------------------
// K5: per-node aggregation. One 128-thread block per (b,n); thread u owns
// output channel u. No fp atomics — CSR bucket walk, fp32 register accumulate.
__global__ void k_agg(const float* __restrict__ support, const int* __restrict__ node_mask,
                      const int* __restrict__ offsets, const int* __restrict__ counts,
                      const float* __restrict__ isd, const int* __restrict__ bucket,
                      const float* __restrict__ bias, float* __restrict__ out) {
    int u  = threadIdx.x;
    int bn = blockIdx.x;               // b*N_ + n
    int b  = bn / N_;
    int start = offsets[bn];
    int cnt   = counts[bn];
    float isd_n = isd[bn];
    int nm = node_mask[bn];
    // self-loop contribution: nm * isd_n * supp[n,u]
    float acc = nm ? isd_n * support[(size_t)bn * U_ + u] : 0.f;
    const int* bk = bucket + (size_t)b * E_;
    for (int t = 0; t < cnt; ++t) {
        int m = bk[start + t];
        acc = fmaf(isd[b * N_ + m], support[(size_t)(b * N_ + m) * U_ + u], acc);
    }
    out[(size_t)bn * U_ + u] = nm ? fmaf(isd_n, acc, bias[u]) : 0.f;
}

// ---------------------------------------------------------------------------
extern "C" void kernel_launch(void* const* d_in, const int* in_sizes, int n_in,
                              void* d_out, int out_size, void* d_ws, size_t ws_size,
                              hipStream_t stream) {
    const float* x         = (const float*)d_in[0];
    const int*   node_mask = (const int*)d_in[1];
    const int*   edge_index= (const int*)d_in[2];
    const int*   edge_mask = (const int*)d_in[3];
    const float* kern      = (const float*)d_in[4];
    const float* bias      = (const float*)d_in[5];
    float*       out       = (float*)d_out;

    char* ws = (char*)d_ws;
    size_t off = 0;
    float* support = (float*)(ws + off); off += (size_t)B_ * N_ * U_ * sizeof(float);
    int*   counts  = (int*)(ws + off);   off += (size_t)B_ * N_ * sizeof(int);
    int*   offsets = (int*)(ws + off);   off += (size_t)B_ * N_ * sizeof(int);
    int*   cursor  = (int*)(ws + off);   off += (size_t)B_ * N_ * sizeof(int);
    float* isd     = (float*)(ws + off); off += (size_t)B_ * N_ * sizeof(float);
    int*   bucket  = (int*)(ws + off);   off += (size_t)B_ * E_ * sizeof(int);

    k_support<<<B_ * N_ / 8, 128, 0, stream>>>(x, kern, support, counts);
    k_count<<<(B_ * E_ + 255) / 256, 256, 0, stream>>>(edge_index, edge_mask, counts);
    k_scan<<<B_, N_, 0, stream>>>(counts, node_mask, offsets, cursor, isd);
    k_fill<<<(B_ * E_ + 255) / 256, 256, 0, stream>>>(edge_index, edge_mask, cursor, bucket);
    k_agg<<<B_ * N_, 128, 0, stream>>>(support, node_mask, offsets, counts, isd, bucket, bias, out);
}